// Round 2
// baseline (132.442 us; speedup 1.0000x reference)
//
#include <hip/hip_runtime.h>
#include <hip/hip_bf16.h>

// Attention_82841329205539: B=2, N=2048, C=768, H=12, D=64, window=129
// Inputs fp32 (dict order), OUTPUT fp32 [B,N,C].
// r6:1485 r7:809 r8:444 r10:270 r11:275 r12:253 r13:166.6 r14:159.9 r15:131.4 us.
// r15 analysis: top-5 all poison fills (44.5us fixed); kernels ~87us.
// This round: qkv 128x64 -> 128x128 m97 structure (MFMA:ds 16:8); swin K via
// clamped global_load_lds + XOR swizzle (mask-after-MFMA makes clamped rows
// safe), Vt transpose-store granule swizzle (kills 8-way bank conflict,
// VST=200), bijective XCD swizzle on swin grid (80% window overlap -> L2).
#define Bsz   2
#define Nseq  2048
#define Cdim  768
#define E3    2304
#define Hh    12
#define Dd    64
#define HALF  64
#define SCALEF 0.125f

typedef __attribute__((ext_vector_type(8))) short short8;
typedef __attribute__((ext_vector_type(4))) float f32x4;

__device__ __forceinline__ unsigned short f2bf(float f) {
    unsigned int u = __float_as_uint(f);
    u = (u + 0x7FFFu + ((u >> 16) & 1u)) >> 16;
    return (unsigned short)u;
}
__device__ __forceinline__ unsigned int pk2(float a, float b) {
    __hip_bfloat162 h = __float22bfloat162_rn(make_float2(a, b));
    union { __hip_bfloat162 h2; unsigned int u; } cv; cv.h2 = h; return cv.u;
}
__device__ __forceinline__ uint4 cvt8(const float4& lo, const float4& hi) {
    return make_uint4(pk2(lo.x, lo.y), pk2(lo.z, lo.w),
                      pk2(hi.x, hi.y), pk2(hi.z, hi.w));
}

// global -> LDS direct DMA, 16B per lane. LDS dest wave-uniform base +
// lane*16 (linear); global src per-lane (carries the swizzle).
__device__ __forceinline__ void gl_lds16(const unsigned short* g, unsigned short* l) {
    __builtin_amdgcn_global_load_lds(
        (__attribute__((address_space(1))) void*)(g),
        (__attribute__((address_space(3))) void*)(l), 16, 0, 0);
}

// ---------------------------------------------------------------------------
// Kernel 0: fp32 -> bf16 pre-convert (x, w_qkv, w_proj).
// ---------------------------------------------------------------------------
__global__ __launch_bounds__(256) void cvt3(
    const float* __restrict__ x, const float* __restrict__ wq,
    const float* __restrict__ wp, unsigned short* __restrict__ xb,
    unsigned short* __restrict__ wqb, unsigned short* __restrict__ wpb)
{
    const int gid = blockIdx.x * 256 + threadIdx.x;   // 0..688127
    const float* src; unsigned short* dst; int off;
    if (gid < 393216)      { src = x;  dst = xb;  off = gid; }
    else if (gid < 614400) { src = wq; dst = wqb; off = gid - 393216; }
    else                   { src = wp; dst = wpb; off = gid - 614400; }
    const float4 lo = *(const float4*)&src[(size_t)off * 8];
    const float4 hi = *(const float4*)&src[(size_t)off * 8 + 4];
    *(uint4*)&dst[(size_t)off * 8] = cvt8(lo, hi);
}

// ---------------------------------------------------------------------------
// Kernel 1: QKV GEMM, pure bf16. 128Mx128N, BK=64 (m97 structure):
// global_load_lds staging, XOR-swizzled LDS, 4 waves each 64x64 (acc 4x4),
// 16 MFMA : 8 ds_read_b128 per wave per K-step. LDS 32KB. grid 576 blocks
// (18x32), bijective XCD swizzle (576 = 8*72).
// ---------------------------------------------------------------------------
__global__ __launch_bounds__(256) void qkv_mfma(
    const unsigned short* __restrict__ xb, const unsigned short* __restrict__ wqb,
    unsigned short* __restrict__ qkvb)
{
    __shared__ __align__(16) unsigned short smem[16384];   // 32 KB
    unsigned short* Asm = smem;          // [128][64] swizzled
    unsigned short* Bsm = smem + 8192;   // [128][64] swizzled

    const int t  = threadIdx.x;
    const int id = blockIdx.y * 18 + blockIdx.x;
    const int p8 = id & 7, j8 = id >> 3;           // 72 tiles per XCD
    const int wg = p8 * 72 + j8;
    const int by = wg / 18, bx = wg % 18;
    const int row0 = by * 128, col0 = bx * 128;

    const int lane = t & 63, wave = t >> 6;
    const int wm = wave >> 1, wn = wave & 1;
    const int ln = lane & 15, quad = lane >> 4;
    const int lr  = lane >> 3;
    const int sc  = ((lane ^ lr) & 7) * 8;         // pre-swizzled src col (shorts)
    const int xsw = (ln & 7) << 3;                 // read-side XOR (shorts)

    f32x4 acc[4][4] = {};

    for (int k0 = 0; k0 < Cdim; k0 += 64) {
        __syncthreads();                 // prev-iter LDS reads complete
#pragma unroll
        for (int j = 0; j < 4; ++j) {    // wave stages rows wave*32..+31 of A,B
            gl_lds16(&xb[(size_t)(row0 + wave*32 + j*8 + lr) * Cdim + k0 + sc],
                     &Asm[(wave*4 + j) * 512]);
            gl_lds16(&wqb[(size_t)(col0 + wave*32 + j*8 + lr) * Cdim + k0 + sc],
                     &Bsm[(wave*4 + j) * 512]);
        }
        __syncthreads();                 // vmcnt(0) drain -> tile ready
#pragma unroll
        for (int kk = 0; kk < 2; ++kk) {
            short8 af[4], bf[4];
#pragma unroll
            for (int mi = 0; mi < 4; ++mi)
                af[mi] = *(const short8*)&Asm[(wm*64 + mi*16 + ln)*64
                                              + ((kk*32 + quad*8) ^ xsw)];
#pragma unroll
            for (int ni = 0; ni < 4; ++ni)
                bf[ni] = *(const short8*)&Bsm[(wn*64 + ni*16 + ln)*64
                                              + ((kk*32 + quad*8) ^ xsw)];
#pragma unroll
            for (int mi = 0; mi < 4; ++mi)
#pragma unroll
                for (int ni = 0; ni < 4; ++ni)
                    acc[mi][ni] = __builtin_amdgcn_mfma_f32_16x16x32_bf16(
                        af[mi], bf[ni], acc[mi][ni], 0, 0, 0);
        }
    }

    // epilogue: two 64-col passes via LDS (waves with wn==p own pass p cols)
    unsigned short (*Cs)[72] = (unsigned short(*)[72])smem;   // 128x72 = 18432 B
    const int rA = t >> 3, c8 = t & 7;
#pragma unroll
    for (int p = 0; p < 2; ++p) {
        __syncthreads();
        if (wn == p) {
#pragma unroll
            for (int mi = 0; mi < 4; ++mi)
#pragma unroll
                for (int ni = 0; ni < 4; ++ni)
#pragma unroll
                    for (int reg = 0; reg < 4; ++reg)
                        Cs[wm*64 + mi*16 + quad*4 + reg][ni*16 + ln] =
                            f2bf(acc[mi][ni][reg]);
        }
        __syncthreads();
#pragma unroll
        for (int j = 0; j < 4; ++j)
            *(uint4*)&qkvb[(size_t)(row0 + rA + j*32) * E3 + col0 + p*64 + c8*8] =
                *(const uint4*)&Cs[rA + j*32][c8*8];
    }
}

// ---------------------------------------------------------------------------
// Kernel 3: output projection + bias -> fp32. 64x64 tile, BK=64, both
// operands bf16 via global_load_lds + swizzle. LDS 16KB. grid (12,64).
// ---------------------------------------------------------------------------
__global__ __launch_bounds__(256) void proj_mfma(
    const unsigned short* __restrict__ Ab, const unsigned short* __restrict__ wpb,
    const float* __restrict__ bias, float* __restrict__ out)
{
    __shared__ __align__(16) unsigned short smem[8192];   // 16 KB
    unsigned short* Asm = smem;          // [64][64] swizzled
    unsigned short* Bsm = smem + 4096;   // [64][64] swizzled

    const int t  = threadIdx.x;
    const int id = blockIdx.y * 12 + blockIdx.x;
    const int p8 = id & 7, j2 = id >> 3;
    const int bx = j2 % 12;
    const int by = p8 * 8 + j2 / 12;
    const int row0 = by * 64, col0 = bx * 64;

    const int lane = t & 63, wave = t >> 6;
    const int ln = lane & 15, quad = lane >> 4;
    const int lr  = lane >> 3;
    const int sc  = ((lane ^ lr) & 7) * 8;
    const int xsw = (ln & 7) << 3;

    f32x4 acc[4] = {};

    for (int k0 = 0; k0 < Cdim; k0 += 64) {
        __syncthreads();
#pragma unroll
        for (int j = 0; j < 2; ++j) {
            const int r = wave*16 + j*8 + lr;
            gl_lds16(&Ab[(size_t)(row0 + r) * Cdim + k0 + sc],
                     &Asm[(wave*2 + j) * 512]);
            gl_lds16(&wpb[(size_t)(col0 + r) * Cdim + k0 + sc],
                     &Bsm[(wave*2 + j) * 512]);
        }
        __syncthreads();
#pragma unroll
        for (int kc = 0; kc < 2; ++kc) {
            short8 af = *(const short8*)&Asm[(wave*16 + ln)*64
                                             + ((kc*32 + quad*8) ^ xsw)];
#pragma unroll
            for (int ni = 0; ni < 4; ++ni) {
                short8 bf = *(const short8*)&Bsm[(ni*16 + ln)*64
                                                 + ((kc*32 + quad*8) ^ xsw)];
                acc[ni] = __builtin_amdgcn_mfma_f32_16x16x32_bf16(af, bf, acc[ni], 0, 0, 0);
            }
        }
    }

    // epilogue: two 32-col fp32 passes via LDS, fused bias
    float (*Csf)[36] = (float(*)[36])smem;   // 64 x 36 fp32 = 9216 B
#pragma unroll
    for (int p = 0; p < 2; ++p) {
        __syncthreads();
#pragma unroll
        for (int ni = 0; ni < 2; ++ni) {
            const int nn = p * 2 + ni;
#pragma unroll
            for (int reg = 0; reg < 4; ++reg)
                Csf[wave*16 + quad*4 + reg][ni*16 + ln] = acc[nn][reg];
        }
        __syncthreads();
#pragma unroll
        for (int j = 0; j < 2; ++j) {
            const int F = t + j * 256, r = F >> 3, c4 = F & 7;
            const int col = col0 + p * 32 + c4 * 4;
            float4 v  = *(const float4*)&Csf[r][c4 * 4];
            float4 bv = *(const float4*)&bias[col];
            *(float4*)&out[(size_t)(row0 + r) * Cdim + col] =
                make_float4(v.x + bv.x, v.y + bv.y, v.z + bv.z, v.w + bv.w);
        }
    }
}

// ---------------------------------------------------------------------------
// Kernel 2: MFMA sliding-window attention.
// K staged via clamped global_load_lds + XOR swizzle (invalid cols masked
// post-MFMA, so clamped-row garbage only hits masked scores). Vt overlay on
// the K region with granule swizzle g^=(d>>3), VST=200 (conflict-free
// transpose stores). Bijective XCD swizzle: XCD p8 gets 8 consecutive
// windows per (b,h) -> L2 reuse of the 80%-overlapping K/V panels.
// LDS 37.4KB -> 4 blk/CU. grid (64, 24), 256 thr.
// ---------------------------------------------------------------------------
#define TQ   32
#define ROWS 160
#define VSTn 200   // 100 dwords == 4 mod 32 (rows spread banks), 16B-aligned
#define PST  168

__global__ __launch_bounds__(256) void swin_attn(
    const unsigned short* __restrict__ qkvb, unsigned short* __restrict__ ab)
{
    __shared__ __align__(16) unsigned short SH[64 * VSTn];   // 25600 B (K[160][64] / Vt[64][200] overlay)
    __shared__ __align__(16) unsigned short Pl[TQ][PST];     // 10752 B
    __shared__ float pmax[4][TQ];                            //   512 B
    __shared__ float psum[4][TQ];                            //   512 B

    const int t  = threadIdx.x;
    // bijective XCD swizzle: n -> (xcd p8, window chunk, bh)
    const int n  = blockIdx.y * 64 + blockIdx.x;
    const int p8 = n & 7, jj8 = n >> 3;
    const int bh = jj8 >> 3;
    const int i0 = (p8 * 8 + (jj8 & 7)) * TQ;
    const int b  = bh / Hh, h = bh % Hh;
    const int hoff = h * Dd;

    const int lane = t & 63, wave = t >> 6;
    const int ln = lane & 15, quad = lane >> 4;
    const int mi    = wave & 1;     // query half (S phase)
    const int khalf = wave >> 1;    // key half (S phase)
    const int lr   = lane >> 3;
    const int scw  = ((lane ^ lr) & 7) * 8;   // pre-swizzled src col (shorts)
    const int xsw  = (ln & 7) << 3;           // read-side XOR

    // ---- prefetch: Q frags (regs), V rows (regs); K -> LDS via DMA
    short8 qf[2];
#pragma unroll
    for (int kc = 0; kc < 2; ++kc)
        qf[kc] = *(const short8*)&qkvb[(size_t)(b * Nseq + i0 + mi*16 + ln) * E3
                                       + hoff + kc*32 + quad*8];
    uint4 vreg[5];
    const int rV = t >> 3, c8 = t & 7;
#pragma unroll
    for (int j = 0; j < 5; ++j) {
        const int r = rV + j * 32;            // key row 0..159
        const int g = i0 - HALF + r;
        uint4 v = make_uint4(0u, 0u, 0u, 0u);
        if (g >= 0 && g < Nseq)
            v = *(const uint4*)&qkvb[(size_t)(b * Nseq + g) * E3 + 2*Cdim + hoff + c8*8];
        vreg[j] = v;
    }
    // K: 5 wave-level DMAs, 8 rows each; clamped source (masked post-MFMA)
#pragma unroll
    for (int j = 0; j < 5; ++j) {
        const int base = j * 32 + wave * 8;   // multiple of 8 -> row&7 == lr&7
        int g = i0 - HALF + base + lr;
        g = min(max(g, 0), Nseq - 1);
        gl_lds16(&qkvb[(size_t)(b * Nseq + g) * E3 + Cdim + hoff + scw],
                 &SH[base * 64]);
    }
    __syncthreads();

    // ---- S phase (K fragments from swizzled linear [160][64])
    f32x4 sacc[5] = {};
#pragma unroll
    for (int kc = 0; kc < 2; ++kc)
#pragma unroll
        for (int tt = 0; tt < 5; ++tt) {
            short8 kf = *(const short8*)&SH[((khalf*5 + tt)*16 + ln)*64
                                            + ((kc*32 + quad*8) ^ xsw)];
            sacc[tt] = __builtin_amdgcn_mfma_f32_16x16x32_bf16(qf[kc], kf, sacc[tt], 0, 0, 0);
        }

    float p[5][4];
    float pm[4] = {-1e30f, -1e30f, -1e30f, -1e30f};
#pragma unroll
    for (int tt = 0; tt < 5; ++tt) {
        const int j = (khalf*5 + tt)*16 + ln;
        const int g = i0 - HALF + j;
#pragma unroll
        for (int reg = 0; reg < 4; ++reg) {
            const int q = mi*16 + quad*4 + reg;
            const bool valid = (j >= q) && (j <= q + 2*HALF) && (g >= 0) && (g < Nseq);
            const float s = valid ? sacc[tt][reg] * SCALEF : -1e30f;
            p[tt][reg] = s;
            pm[reg] = fmaxf(pm[reg], s);
        }
    }
#pragma unroll
    for (int reg = 0; reg < 4; ++reg) {
        pm[reg] = fmaxf(pm[reg], __shfl_xor(pm[reg], 1));
        pm[reg] = fmaxf(pm[reg], __shfl_xor(pm[reg], 2));
        pm[reg] = fmaxf(pm[reg], __shfl_xor(pm[reg], 4));
        pm[reg] = fmaxf(pm[reg], __shfl_xor(pm[reg], 8));
    }
    if (ln == 0)
#pragma unroll
        for (int reg = 0; reg < 4; ++reg)
            pmax[wave][mi*16 + quad*4 + reg] = pm[reg];
    __syncthreads();   // pmax ready; all K reads complete (Vt overlay safe)

    // ---- exp, row sums, write P; overwrite K region with Vt
    float ps[4] = {};
#pragma unroll
    for (int reg = 0; reg < 4; ++reg) {
        const int q = mi*16 + quad*4 + reg;
        const float cm = fmaxf(pmax[mi][q], pmax[mi | 2][q]);
#pragma unroll
        for (int tt = 0; tt < 5; ++tt) {
            const float pv = (p[tt][reg] > -1e29f) ? __expf(p[tt][reg] - cm) : 0.f;
            p[tt][reg] = pv;
            ps[reg] += pv;
        }
    }
#pragma unroll
    for (int reg = 0; reg < 4; ++reg) {
        ps[reg] += __shfl_xor(ps[reg], 1);
        ps[reg] += __shfl_xor(ps[reg], 2);
        ps[reg] += __shfl_xor(ps[reg], 4);
        ps[reg] += __shfl_xor(ps[reg], 8);
    }
    if (ln == 0)
#pragma unroll
        for (int reg = 0; reg < 4; ++reg)
            psum[wave][mi*16 + quad*4 + reg] = ps[reg];
#pragma unroll
    for (int tt = 0; tt < 5; ++tt)
#pragma unroll
        for (int reg = 0; reg < 4; ++reg)
            Pl[mi*16 + quad*4 + reg][(khalf*5 + tt)*16 + ln] = f2bf(p[tt][reg]);
    // Vt[d][key] transpose stores, granule-swizzled: column granule ^= d>>3
    // (= c8) -> 8 distinct banks across the conflicting c8 lanes.
#pragma unroll
    for (int j = 0; j < 5; ++j) {
        const int r = rV + j * 32;
        const int gr = ((r >> 3) ^ c8) * 8 + (r & 7);
        union { unsigned short us[8]; uint4 u; } pk; pk.u = vreg[j];
#pragma unroll
        for (int d8 = 0; d8 < 8; ++d8)
            SH[(c8 * 8 + d8) * VSTn + gr] = pk.us[d8];
    }
    __syncthreads();

    // ---- PV phase: D[m=dim][n=query] = Vt . Pl^T
    const int niq = wave & 1;
    const int mb  = (wave >> 1) * 2;
    f32x4 oacc[2] = {};
#pragma unroll
    for (int kc = 0; kc < 5; ++kc) {
        short8 pf = *(const short8*)&Pl[niq*16 + ln][kc*32 + quad*8];
#pragma unroll
        for (int m2 = 0; m2 < 2; ++m2) {
            const int d = (mb + m2)*16 + ln;
            short8 vf = *(const short8*)&SH[d * VSTn
                                            + (((kc*4 + quad) ^ (d >> 3)) << 3)];
            oacc[m2] = __builtin_amdgcn_mfma_f32_16x16x32_bf16(vf, pf, oacc[m2], 0, 0, 0);
        }
    }

    const int q = niq*16 + ln;
    const float inv = 1.f / (psum[q >> 4][q] + psum[(q >> 4) | 2][q]);
    unsigned short* orow = &ab[(size_t)(b * Nseq + i0 + q) * Cdim + hoff];
#pragma unroll
    for (int m2 = 0; m2 < 2; ++m2) {
        const int d0 = (mb + m2)*16 + quad*4;
        union { unsigned short us[4]; uint2 u2; } pk;
#pragma unroll
        for (int reg = 0; reg < 4; ++reg)
            pk.us[reg] = f2bf(oacc[m2][reg] * inv);
        *(uint2*)&orow[d0] = pk.u2;
    }
}

// ---------------------------------------------------------------------------
extern "C" void kernel_launch(void* const* d_in, const int* in_sizes, int n_in,
                              void* d_out, int out_size, void* d_ws, size_t ws_size,
                              hipStream_t stream)
{
    const float* x      = (const float*)d_in[0];
    const float* w_qkv  = (const float*)d_in[1];
    const float* w_proj = (const float*)d_in[2];
    const float* b_proj = (const float*)d_in[3];
    float* out = (float*)d_out;

    unsigned short* qkvb = (unsigned short*)d_ws;   // 9,437,184 shorts
    unsigned short* ab   = qkvb + 9437184;          // 3,145,728 shorts
    unsigned short* xb   = ab   + 3145728;          // 3,145,728 shorts
    unsigned short* wqb  = xb   + 3145728;          // 1,769,472 shorts
    unsigned short* wpb  = wqb  + 1769472;          //   589,824 shorts (36.2MB total)

    cvt3<<<dim3(2688), 256, 0, stream>>>(x, w_qkv, w_proj, xb, wqb, wpb);
    qkv_mfma<<<dim3(18, 32), 256, 0, stream>>>(xb, wqb, qkvb);
    swin_attn<<<dim3(Nseq / TQ, Bsz * Hh), 256, 0, stream>>>(qkvb, ab);
    proj_mfma<<<dim3(12, 64), 256, 0, stream>>>(ab, wpb, b_proj, out);
}

// Round 3
// 130.658 us; speedup vs baseline: 1.0137x; 1.0137x over previous
//
#include <hip/hip_runtime.h>
#include <hip/hip_bf16.h>

// Attention_82841329205539: B=2, N=2048, C=768, H=12, D=64, window=129
// Inputs fp32 (dict order), OUTPUT fp32 [B,N,C].
// r6:1485 r7:809 r8:444 r10:270 r11:275 r12:253 r13:166.6 r14:159.9 r15:131.4
// r16:132.4 us. r16 post-mortem: qkv-retile and swin micro-fixes both ~neutral
// -> swin (~40us est.) is latency/overhead-bound, not conflict-bound.
// This round (swin ONLY, isolate attribution): TQ 32->64, 768 blocks,
// wave-owns-full-row softmax (no pmax LDS roundtrip), 3 key-loads/query
// (was 5), per-block MFMA 80->152, LDS 51.4KB -> 3 blk/CU (whole grid
// resident). qkv/proj/cvt3 identical to r16.
#define Bsz   2
#define Nseq  2048
#define Cdim  768
#define E3    2304
#define Hh    12
#define Dd    64
#define HALF  64
#define SCALEF 0.125f

typedef __attribute__((ext_vector_type(8))) short short8;
typedef __attribute__((ext_vector_type(4))) float f32x4;

__device__ __forceinline__ unsigned short f2bf(float f) {
    unsigned int u = __float_as_uint(f);
    u = (u + 0x7FFFu + ((u >> 16) & 1u)) >> 16;
    return (unsigned short)u;
}
__device__ __forceinline__ unsigned int pk2(float a, float b) {
    __hip_bfloat162 h = __float22bfloat162_rn(make_float2(a, b));
    union { __hip_bfloat162 h2; unsigned int u; } cv; cv.h2 = h; return cv.u;
}
__device__ __forceinline__ uint4 cvt8(const float4& lo, const float4& hi) {
    return make_uint4(pk2(lo.x, lo.y), pk2(lo.z, lo.w),
                      pk2(hi.x, hi.y), pk2(hi.z, hi.w));
}

// global -> LDS direct DMA, 16B per lane. LDS dest wave-uniform base +
// lane*16 (linear); global src per-lane (carries the swizzle).
__device__ __forceinline__ void gl_lds16(const unsigned short* g, unsigned short* l) {
    __builtin_amdgcn_global_load_lds(
        (__attribute__((address_space(1))) void*)(g),
        (__attribute__((address_space(3))) void*)(l), 16, 0, 0);
}

// ---------------------------------------------------------------------------
// Kernel 0: fp32 -> bf16 pre-convert (x, w_qkv, w_proj).
// ---------------------------------------------------------------------------
__global__ __launch_bounds__(256) void cvt3(
    const float* __restrict__ x, const float* __restrict__ wq,
    const float* __restrict__ wp, unsigned short* __restrict__ xb,
    unsigned short* __restrict__ wqb, unsigned short* __restrict__ wpb)
{
    const int gid = blockIdx.x * 256 + threadIdx.x;   // 0..688127
    const float* src; unsigned short* dst; int off;
    if (gid < 393216)      { src = x;  dst = xb;  off = gid; }
    else if (gid < 614400) { src = wq; dst = wqb; off = gid - 393216; }
    else                   { src = wp; dst = wpb; off = gid - 614400; }
    const float4 lo = *(const float4*)&src[(size_t)off * 8];
    const float4 hi = *(const float4*)&src[(size_t)off * 8 + 4];
    *(uint4*)&dst[(size_t)off * 8] = cvt8(lo, hi);
}

// ---------------------------------------------------------------------------
// Kernel 1: QKV GEMM, pure bf16. 128Mx128N, BK=64 (m97 structure).
// ---------------------------------------------------------------------------
__global__ __launch_bounds__(256) void qkv_mfma(
    const unsigned short* __restrict__ xb, const unsigned short* __restrict__ wqb,
    unsigned short* __restrict__ qkvb)
{
    __shared__ __align__(16) unsigned short smem[16384];   // 32 KB
    unsigned short* Asm = smem;          // [128][64] swizzled
    unsigned short* Bsm = smem + 8192;   // [128][64] swizzled

    const int t  = threadIdx.x;
    const int id = blockIdx.y * 18 + blockIdx.x;
    const int p8 = id & 7, j8 = id >> 3;           // 72 tiles per XCD
    const int wg = p8 * 72 + j8;
    const int by = wg / 18, bx = wg % 18;
    const int row0 = by * 128, col0 = bx * 128;

    const int lane = t & 63, wave = t >> 6;
    const int wm = wave >> 1, wn = wave & 1;
    const int ln = lane & 15, quad = lane >> 4;
    const int lr  = lane >> 3;
    const int sc  = ((lane ^ lr) & 7) * 8;         // pre-swizzled src col (shorts)
    const int xsw = (ln & 7) << 3;                 // read-side XOR (shorts)

    f32x4 acc[4][4] = {};

    for (int k0 = 0; k0 < Cdim; k0 += 64) {
        __syncthreads();                 // prev-iter LDS reads complete
#pragma unroll
        for (int j = 0; j < 4; ++j) {    // wave stages rows wave*32..+31 of A,B
            gl_lds16(&xb[(size_t)(row0 + wave*32 + j*8 + lr) * Cdim + k0 + sc],
                     &Asm[(wave*4 + j) * 512]);
            gl_lds16(&wqb[(size_t)(col0 + wave*32 + j*8 + lr) * Cdim + k0 + sc],
                     &Bsm[(wave*4 + j) * 512]);
        }
        __syncthreads();                 // vmcnt(0) drain -> tile ready
#pragma unroll
        for (int kk = 0; kk < 2; ++kk) {
            short8 af[4], bf[4];
#pragma unroll
            for (int mi = 0; mi < 4; ++mi)
                af[mi] = *(const short8*)&Asm[(wm*64 + mi*16 + ln)*64
                                              + ((kk*32 + quad*8) ^ xsw)];
#pragma unroll
            for (int ni = 0; ni < 4; ++ni)
                bf[ni] = *(const short8*)&Bsm[(wn*64 + ni*16 + ln)*64
                                              + ((kk*32 + quad*8) ^ xsw)];
#pragma unroll
            for (int mi = 0; mi < 4; ++mi)
#pragma unroll
                for (int ni = 0; ni < 4; ++ni)
                    acc[mi][ni] = __builtin_amdgcn_mfma_f32_16x16x32_bf16(
                        af[mi], bf[ni], acc[mi][ni], 0, 0, 0);
        }
    }

    // epilogue: two 64-col passes via LDS (waves with wn==p own pass p cols)
    unsigned short (*Cs)[72] = (unsigned short(*)[72])smem;   // 128x72 = 18432 B
    const int rA = t >> 3, c8 = t & 7;
#pragma unroll
    for (int p = 0; p < 2; ++p) {
        __syncthreads();
        if (wn == p) {
#pragma unroll
            for (int mi = 0; mi < 4; ++mi)
#pragma unroll
                for (int ni = 0; ni < 4; ++ni)
#pragma unroll
                    for (int reg = 0; reg < 4; ++reg)
                        Cs[wm*64 + mi*16 + quad*4 + reg][ni*16 + ln] =
                            f2bf(acc[mi][ni][reg]);
        }
        __syncthreads();
#pragma unroll
        for (int j = 0; j < 4; ++j)
            *(uint4*)&qkvb[(size_t)(row0 + rA + j*32) * E3 + col0 + p*64 + c8*8] =
                *(const uint4*)&Cs[rA + j*32][c8*8];
    }
}

// ---------------------------------------------------------------------------
// Kernel 3: output projection + bias -> fp32. 64x64 tile, BK=64.
// ---------------------------------------------------------------------------
__global__ __launch_bounds__(256) void proj_mfma(
    const unsigned short* __restrict__ Ab, const unsigned short* __restrict__ wpb,
    const float* __restrict__ bias, float* __restrict__ out)
{
    __shared__ __align__(16) unsigned short smem[8192];   // 16 KB
    unsigned short* Asm = smem;          // [64][64] swizzled
    unsigned short* Bsm = smem + 4096;   // [64][64] swizzled

    const int t  = threadIdx.x;
    const int id = blockIdx.y * 12 + blockIdx.x;
    const int p8 = id & 7, j2 = id >> 3;
    const int bx = j2 % 12;
    const int by = p8 * 8 + j2 / 12;
    const int row0 = by * 64, col0 = bx * 64;

    const int lane = t & 63, wave = t >> 6;
    const int ln = lane & 15, quad = lane >> 4;
    const int lr  = lane >> 3;
    const int sc  = ((lane ^ lr) & 7) * 8;
    const int xsw = (ln & 7) << 3;

    f32x4 acc[4] = {};

    for (int k0 = 0; k0 < Cdim; k0 += 64) {
        __syncthreads();
#pragma unroll
        for (int j = 0; j < 2; ++j) {
            const int r = wave*16 + j*8 + lr;
            gl_lds16(&Ab[(size_t)(row0 + r) * Cdim + k0 + sc],
                     &Asm[(wave*2 + j) * 512]);
            gl_lds16(&wpb[(size_t)(col0 + r) * Cdim + k0 + sc],
                     &Bsm[(wave*2 + j) * 512]);
        }
        __syncthreads();
#pragma unroll
        for (int kc = 0; kc < 2; ++kc) {
            short8 af = *(const short8*)&Asm[(wave*16 + ln)*64
                                             + ((kc*32 + quad*8) ^ xsw)];
#pragma unroll
            for (int ni = 0; ni < 4; ++ni) {
                short8 bf = *(const short8*)&Bsm[(ni*16 + ln)*64
                                                 + ((kc*32 + quad*8) ^ xsw)];
                acc[ni] = __builtin_amdgcn_mfma_f32_16x16x32_bf16(af, bf, acc[ni], 0, 0, 0);
            }
        }
    }

    // epilogue: two 32-col fp32 passes via LDS, fused bias
    float (*Csf)[36] = (float(*)[36])smem;   // 64 x 36 fp32 = 9216 B
#pragma unroll
    for (int p = 0; p < 2; ++p) {
        __syncthreads();
#pragma unroll
        for (int ni = 0; ni < 2; ++ni) {
            const int nn = p * 2 + ni;
#pragma unroll
            for (int reg = 0; reg < 4; ++reg)
                Csf[wave*16 + quad*4 + reg][ni*16 + ln] = acc[nn][reg];
        }
        __syncthreads();
#pragma unroll
        for (int j = 0; j < 2; ++j) {
            const int F = t + j * 256, r = F >> 3, c4 = F & 7;
            const int col = col0 + p * 32 + c4 * 4;
            float4 v  = *(const float4*)&Csf[r][c4 * 4];
            float4 bv = *(const float4*)&bias[col];
            *(float4*)&out[(size_t)(row0 + r) * Cdim + col] =
                make_float4(v.x + bv.x, v.y + bv.y, v.z + bv.z, v.w + bv.w);
        }
    }
}

// ---------------------------------------------------------------------------
// Kernel 2: sliding-window attention, TQ=64 per block, 4 waves.
// Wave w owns 16 query rows (wave*16..+15) end-to-end: S over its 9 key
// tiles [w, w+8], register softmax (shfl-only row reduce), P store, PV for
// the same 16 queries. K[192][64] DMA-staged (clamped rows; masked post-
// MFMA), Vt[64][200] granule-swizzled overlay on K. psum[64] LDS for the
// PV normalizer. 3 barriers; LDS 51.4KB -> 3 blk/CU; grid 768 (whole grid
// resident), bijective XCD swizzle (4 consecutive windows/XCD per bh).
// ---------------------------------------------------------------------------
#define TQ2  64
#define KR   192
#define VSTn 200   // 100 dwords == 4 mod 32; granules: 25 >= 24 reach
#define PSTn 200

__global__ __launch_bounds__(256) void swin_attn(
    const unsigned short* __restrict__ qkvb, unsigned short* __restrict__ ab)
{
    __shared__ __align__(16) unsigned short SH[64 * VSTn];   // 25600B K/Vt overlay
    __shared__ __align__(16) unsigned short Pl[TQ2][PSTn];   // 25600B
    __shared__ float psum[TQ2];                              //   256B

    const int t  = threadIdx.x;
    const int id = blockIdx.y * 32 + blockIdx.x;   // 768 blocks
    const int p8 = id & 7, j8 = id >> 3;           // 96 per XCD
    const int bh = j8 >> 2;
    const int i0 = (p8 * 4 + (j8 & 3)) * TQ2;
    const int b  = bh / Hh, h = bh % Hh;
    const int hoff = h * Dd;

    const int lane = t & 63, wave = t >> 6;
    const int ln = lane & 15, quad = lane >> 4;
    const int lr  = lane >> 3;
    const int scw = ((lane ^ lr) & 7) * 8;   // pre-swizzled src col (shorts)
    const int xsw = (ln & 7) << 3;           // read-side XOR
    const int rV  = t >> 3, c8 = t & 7;

    // ---- Q fragments (wave's 16 query rows)
    short8 qf[2];
#pragma unroll
    for (int kc = 0; kc < 2; ++kc)
        qf[kc] = *(const short8*)&qkvb[(size_t)(b * Nseq + i0 + wave*16 + ln) * E3
                                       + hoff + kc*32 + quad*8];

    // ---- V rows -> regs (clamped; P==0 exactly on masked/OOB keys)
    uint4 vreg[6];
#pragma unroll
    for (int j = 0; j < 6; ++j) {
        int g = i0 - HALF + rV + j*32;
        g = min(max(g, 0), Nseq - 1);
        vreg[j] = *(const uint4*)&qkvb[(size_t)(b * Nseq + g) * E3 + 2*Cdim + hoff + c8*8];
    }

    // ---- K -> LDS via DMA (24 x 8-row groups; clamped rows)
#pragma unroll
    for (int j = 0; j < 6; ++j) {
        const int base = (j*4 + wave) * 8;
        int g = i0 - HALF + base + lr;
        g = min(max(g, 0), Nseq - 1);
        gl_lds16(&qkvb[(size_t)(b * Nseq + g) * E3 + Cdim + hoff + scw],
                 &SH[base * 64]);
    }
    __syncthreads();

    // ---- S phase: wave's queries need key tiles [wave, wave+8]
    f32x4 sacc[9] = {};
#pragma unroll
    for (int kc = 0; kc < 2; ++kc)
#pragma unroll
        for (int tt = 0; tt < 9; ++tt) {
            short8 kf = *(const short8*)&SH[((wave + tt)*16 + ln)*64
                                            + ((kc*32 + quad*8) ^ xsw)];
            sacc[tt] = __builtin_amdgcn_mfma_f32_16x16x32_bf16(qf[kc], kf, sacc[tt], 0, 0, 0);
        }

    // ---- mask + row max, all register-local (wave owns full rows)
    float pm[4] = {-1e30f, -1e30f, -1e30f, -1e30f};
#pragma unroll
    for (int tt = 0; tt < 9; ++tt) {
        const int r = (wave + tt)*16 + ln;
        const int g = i0 - HALF + r;
#pragma unroll
        for (int reg = 0; reg < 4; ++reg) {
            const int q = wave*16 + quad*4 + reg;
            const bool valid = (r >= q) && (r <= q + 2*HALF) && (g >= 0) && (g < Nseq);
            const float s = valid ? sacc[tt][reg] * SCALEF : -1e30f;
            sacc[tt][reg] = s;
            pm[reg] = fmaxf(pm[reg], s);
        }
    }
#pragma unroll
    for (int reg = 0; reg < 4; ++reg) {
        pm[reg] = fmaxf(pm[reg], __shfl_xor(pm[reg], 1));
        pm[reg] = fmaxf(pm[reg], __shfl_xor(pm[reg], 2));
        pm[reg] = fmaxf(pm[reg], __shfl_xor(pm[reg], 4));
        pm[reg] = fmaxf(pm[reg], __shfl_xor(pm[reg], 8));
    }
    float ps[4] = {};
#pragma unroll
    for (int reg = 0; reg < 4; ++reg)
#pragma unroll
        for (int tt = 0; tt < 9; ++tt) {
            const float pv = (sacc[tt][reg] > -1e29f) ? __expf(sacc[tt][reg] - pm[reg]) : 0.f;
            sacc[tt][reg] = pv;
            ps[reg] += pv;
        }
#pragma unroll
    for (int reg = 0; reg < 4; ++reg) {
        ps[reg] += __shfl_xor(ps[reg], 1);
        ps[reg] += __shfl_xor(ps[reg], 2);
        ps[reg] += __shfl_xor(ps[reg], 4);
        ps[reg] += __shfl_xor(ps[reg], 8);
    }

    // ---- P stores (Pl not overlaid -> safe before the K-drain barrier),
    // zero the one covered-but-unwritten boundary tile, psum store.
#pragma unroll
    for (int tt = 0; tt < 9; ++tt)
#pragma unroll
        for (int reg = 0; reg < 4; ++reg)
            Pl[wave*16 + quad*4 + reg][(wave + tt)*16 + ln] = f2bf(sacc[tt][reg]);
    {
        const int tz = (wave & 1) ? (wave - 1) : (wave + 9);
        *(uint2*)&Pl[wave*16 + ln][tz*16 + quad*4] = make_uint2(0u, 0u);
    }
    if (ln == 0)
#pragma unroll
        for (int reg = 0; reg < 4; ++reg)
            psum[wave*16 + quad*4 + reg] = ps[reg];
    __syncthreads();   // all waves' K reads complete -> Vt overlay safe

    // ---- Vt transpose stores, granule-swizzled (2-way banks = free)
#pragma unroll
    for (int j = 0; j < 6; ++j) {
        const int r = rV + j*32;
        const int gr = ((r >> 3) ^ c8)*8 + (r & 7);
        union { unsigned short us[8]; uint4 u; } pk; pk.u = vreg[j];
#pragma unroll
        for (int d8 = 0; d8 < 8; ++d8)
            SH[(c8*8 + d8)*VSTn + gr] = pk.us[d8];
    }
    __syncthreads();

    // ---- PV: wave's own 16 queries (cols), all 64 dims, 5 kc blocks
    const int kc0 = wave >> 1;
    f32x4 oacc[4] = {};
#pragma unroll
    for (int c = 0; c < 5; ++c) {
        const int kc = kc0 + c;
        short8 pf = *(const short8*)&Pl[wave*16 + ln][kc*32 + quad*8];
#pragma unroll
        for (int m = 0; m < 4; ++m) {
            const int d = m*16 + ln;
            short8 vf = *(const short8*)&SH[d * VSTn
                                            + (((kc*4 + quad) ^ (d >> 3)) << 3)];
            oacc[m] = __builtin_amdgcn_mfma_f32_16x16x32_bf16(vf, pf, oacc[m], 0, 0, 0);
        }
    }

    const int q = wave*16 + ln;
    const float inv = 1.f / psum[q];
    unsigned short* orow = &ab[(size_t)(b * Nseq + i0 + q) * Cdim + hoff];
#pragma unroll
    for (int m = 0; m < 4; ++m) {
        const int d0 = m*16 + quad*4;
        union { unsigned short us[4]; uint2 u2; } pk;
#pragma unroll
        for (int reg = 0; reg < 4; ++reg)
            pk.us[reg] = f2bf(oacc[m][reg] * inv);
        *(uint2*)&orow[d0] = pk.u2;
    }
}

// ---------------------------------------------------------------------------
extern "C" void kernel_launch(void* const* d_in, const int* in_sizes, int n_in,
                              void* d_out, int out_size, void* d_ws, size_t ws_size,
                              hipStream_t stream)
{
    const float* x      = (const float*)d_in[0];
    const float* w_qkv  = (const float*)d_in[1];
    const float* w_proj = (const float*)d_in[2];
    const float* b_proj = (const float*)d_in[3];
    float* out = (float*)d_out;

    unsigned short* qkvb = (unsigned short*)d_ws;   // 9,437,184 shorts
    unsigned short* ab   = qkvb + 9437184;          // 3,145,728 shorts
    unsigned short* xb   = ab   + 3145728;          // 3,145,728 shorts
    unsigned short* wqb  = xb   + 3145728;          // 1,769,472 shorts
    unsigned short* wpb  = wqb  + 1769472;          //   589,824 shorts (36.2MB total)

    cvt3<<<dim3(2688), 256, 0, stream>>>(x, w_qkv, w_proj, xb, wqb, wpb);
    qkv_mfma<<<dim3(18, 32), 256, 0, stream>>>(xb, wqb, qkvb);
    swin_attn<<<dim3(32, Bsz * Hh), 256, 0, stream>>>(qkvb, ab);
    proj_mfma<<<dim3(12, 64), 256, 0, stream>>>(ab, wpb, b_proj, out);
}

// Round 4
// 120.444 us; speedup vs baseline: 1.0996x; 1.0848x over previous
//
#include <hip/hip_runtime.h>
#include <hip/hip_bf16.h>

// Attention_82841329205539: B=2, N=2048, C=768, H=12, D=64, window=129
// Inputs fp32 (dict order), OUTPUT fp32 [B,N,C].
// r6:1485 r7:809 r8:444 r10:270 r11:275 r12:253 r13:166.6 r14:159.9 r15:131.4
// r16:132.4 r17:130.7 us. r17 post-mortem: swin restructure ~neutral (3rd
// failed swin/conflict theory). Re-budget via m102 shape curve: the 2-barrier
// per-K-step GEMM structure runs ~320 TF at this shape -> qkv ~35us, proj
// ~12us ARE the consumers; every K-step drains vmcnt(0) right after issuing
// the stage (full HBM latency exposed, 12x). This round: T3 minimum-2-phase
// on qkv+proj -- double-buffered LDS, prefetch next tile BEFORE compute,
// single __syncthreads per K-step (its implicit vmcnt(0) lands AFTER MFMA).
// swin/cvt3 frozen.
#define Bsz   2
#define Nseq  2048
#define Cdim  768
#define E3    2304
#define Hh    12
#define Dd    64
#define HALF  64
#define SCALEF 0.125f

typedef __attribute__((ext_vector_type(8))) short short8;
typedef __attribute__((ext_vector_type(4))) float f32x4;

__device__ __forceinline__ unsigned short f2bf(float f) {
    unsigned int u = __float_as_uint(f);
    u = (u + 0x7FFFu + ((u >> 16) & 1u)) >> 16;
    return (unsigned short)u;
}
__device__ __forceinline__ unsigned int pk2(float a, float b) {
    __hip_bfloat162 h = __float22bfloat162_rn(make_float2(a, b));
    union { __hip_bfloat162 h2; unsigned int u; } cv; cv.h2 = h; return cv.u;
}
__device__ __forceinline__ uint4 cvt8(const float4& lo, const float4& hi) {
    return make_uint4(pk2(lo.x, lo.y), pk2(lo.z, lo.w),
                      pk2(hi.x, hi.y), pk2(hi.z, hi.w));
}

// global -> LDS direct DMA, 16B per lane. LDS dest wave-uniform base +
// lane*16 (linear); global src per-lane (carries the swizzle).
__device__ __forceinline__ void gl_lds16(const unsigned short* g, unsigned short* l) {
    __builtin_amdgcn_global_load_lds(
        (__attribute__((address_space(1))) void*)(g),
        (__attribute__((address_space(3))) void*)(l), 16, 0, 0);
}

// ---------------------------------------------------------------------------
// Kernel 0: fp32 -> bf16 pre-convert (x, w_qkv, w_proj).
// ---------------------------------------------------------------------------
__global__ __launch_bounds__(256) void cvt3(
    const float* __restrict__ x, const float* __restrict__ wq,
    const float* __restrict__ wp, unsigned short* __restrict__ xb,
    unsigned short* __restrict__ wqb, unsigned short* __restrict__ wpb)
{
    const int gid = blockIdx.x * 256 + threadIdx.x;   // 0..688127
    const float* src; unsigned short* dst; int off;
    if (gid < 393216)      { src = x;  dst = xb;  off = gid; }
    else if (gid < 614400) { src = wq; dst = wqb; off = gid - 393216; }
    else                   { src = wp; dst = wpb; off = gid - 614400; }
    const float4 lo = *(const float4*)&src[(size_t)off * 8];
    const float4 hi = *(const float4*)&src[(size_t)off * 8 + 4];
    *(uint4*)&dst[(size_t)off * 8] = cvt8(lo, hi);
}

// ---------------------------------------------------------------------------
// Kernel 1: QKV GEMM, pure bf16. 128Mx128N, BK=64, DOUBLE-BUFFERED
// global_load_lds staging (T3 2-phase): issue next-tile DMA, then ds_read+
// MFMA current tile, then one __syncthreads (vmcnt(0) drain lands after
// MFMA). LDS 64KB (2 x [128][64]A + [128][64]B swizzled). grid 576 (18x32),
// bijective XCD swizzle.
// ---------------------------------------------------------------------------
__global__ __launch_bounds__(256) void qkv_mfma(
    const unsigned short* __restrict__ xb, const unsigned short* __restrict__ wqb,
    unsigned short* __restrict__ qkvb)
{
    __shared__ __align__(16) unsigned short smem[32768];   // 64 KB, 2 buffers

    const int t  = threadIdx.x;
    const int id = blockIdx.y * 18 + blockIdx.x;
    const int p8 = id & 7, j8 = id >> 3;           // 72 tiles per XCD
    const int wg = p8 * 72 + j8;
    const int by = wg / 18, bx = wg % 18;
    const int row0 = by * 128, col0 = bx * 128;

    const int lane = t & 63, wave = t >> 6;
    const int wm = wave >> 1, wn = wave & 1;
    const int ln = lane & 15, quad = lane >> 4;
    const int lr  = lane >> 3;
    const int sc  = ((lane ^ lr) & 7) * 8;         // pre-swizzled src col (shorts)
    const int xsw = (ln & 7) << 3;                 // read-side XOR (shorts)

    const unsigned short* Ag = &xb [(size_t)(row0 + wave*32 + lr) * Cdim + sc];
    const unsigned short* Bg = &wqb[(size_t)(col0 + wave*32 + lr) * Cdim + sc];

    f32x4 acc[4][4] = {};

    // prologue: stage tile 0 into buffer 0
#pragma unroll
    for (int j = 0; j < 4; ++j) {
        gl_lds16(Ag + (size_t)(j*8) * Cdim, &smem[(wave*4 + j) * 512]);
        gl_lds16(Bg + (size_t)(j*8) * Cdim, &smem[8192 + (wave*4 + j) * 512]);
    }
    __syncthreads();   // vmcnt(0): buffer 0 ready

    int cur = 0;
    for (int k0 = 0; k0 < Cdim; k0 += 64) {
        unsigned short* bc = smem + cur * 16384;
        if (k0 + 64 < Cdim) {           // prefetch next tile into other buffer
            unsigned short* bn = smem + (cur ^ 1) * 16384;
            const int kn = k0 + 64;
#pragma unroll
            for (int j = 0; j < 4; ++j) {
                gl_lds16(Ag + (size_t)(j*8) * Cdim + kn, &bn[(wave*4 + j) * 512]);
                gl_lds16(Bg + (size_t)(j*8) * Cdim + kn, &bn[8192 + (wave*4 + j) * 512]);
            }
        }
#pragma unroll
        for (int kk = 0; kk < 2; ++kk) {
            short8 af[4], bf[4];
#pragma unroll
            for (int mi = 0; mi < 4; ++mi)
                af[mi] = *(const short8*)&bc[(wm*64 + mi*16 + ln)*64
                                             + ((kk*32 + quad*8) ^ xsw)];
#pragma unroll
            for (int ni = 0; ni < 4; ++ni)
                bf[ni] = *(const short8*)&bc[8192 + (wn*64 + ni*16 + ln)*64
                                             + ((kk*32 + quad*8) ^ xsw)];
#pragma unroll
            for (int mi = 0; mi < 4; ++mi)
#pragma unroll
                for (int ni = 0; ni < 4; ++ni)
                    acc[mi][ni] = __builtin_amdgcn_mfma_f32_16x16x32_bf16(
                        af[mi], bf[ni], acc[mi][ni], 0, 0, 0);
        }
        __syncthreads();   // drains prefetch (after MFMA) + read-before-write
        cur ^= 1;
    }

    // epilogue: two 64-col passes via LDS (waves with wn==p own pass p cols)
    unsigned short (*Cs)[72] = (unsigned short(*)[72])smem;   // 128x72 = 18432 B
    const int rA = t >> 3, c8 = t & 7;
#pragma unroll
    for (int p = 0; p < 2; ++p) {
        __syncthreads();
        if (wn == p) {
#pragma unroll
            for (int mi = 0; mi < 4; ++mi)
#pragma unroll
                for (int ni = 0; ni < 4; ++ni)
#pragma unroll
                    for (int reg = 0; reg < 4; ++reg)
                        Cs[wm*64 + mi*16 + quad*4 + reg][ni*16 + ln] =
                            f2bf(acc[mi][ni][reg]);
        }
        __syncthreads();
#pragma unroll
        for (int j = 0; j < 4; ++j)
            *(uint4*)&qkvb[(size_t)(row0 + rA + j*32) * E3 + col0 + p*64 + c8*8] =
                *(const uint4*)&Cs[rA + j*32][c8*8];
    }
}

// ---------------------------------------------------------------------------
// Kernel 3: output projection + bias -> fp32. 64x64 tile, BK=64,
// double-buffered (T3 2-phase), LDS 32KB. grid (12,64).
// ---------------------------------------------------------------------------
__global__ __launch_bounds__(256) void proj_mfma(
    const unsigned short* __restrict__ Ab, const unsigned short* __restrict__ wpb,
    const float* __restrict__ bias, float* __restrict__ out)
{
    __shared__ __align__(16) unsigned short smem[16384];   // 32 KB, 2 buffers

    const int t  = threadIdx.x;
    const int id = blockIdx.y * 12 + blockIdx.x;
    const int p8 = id & 7, j2 = id >> 3;
    const int bx = j2 % 12;
    const int by = p8 * 8 + j2 / 12;
    const int row0 = by * 64, col0 = bx * 64;

    const int lane = t & 63, wave = t >> 6;
    const int ln = lane & 15, quad = lane >> 4;
    const int lr  = lane >> 3;
    const int sc  = ((lane ^ lr) & 7) * 8;
    const int xsw = (ln & 7) << 3;

    const unsigned short* Ag = &Ab [(size_t)(row0 + wave*16 + lr) * Cdim + sc];
    const unsigned short* Bg = &wpb[(size_t)(col0 + wave*16 + lr) * Cdim + sc];

    f32x4 acc[4] = {};

    // prologue: stage tile 0 into buffer 0
#pragma unroll
    for (int j = 0; j < 2; ++j) {
        gl_lds16(Ag + (size_t)(j*8) * Cdim, &smem[(wave*2 + j) * 512]);
        gl_lds16(Bg + (size_t)(j*8) * Cdim, &smem[4096 + (wave*2 + j) * 512]);
    }
    __syncthreads();

    int cur = 0;
    for (int k0 = 0; k0 < Cdim; k0 += 64) {
        unsigned short* bc = smem + cur * 8192;
        if (k0 + 64 < Cdim) {
            unsigned short* bn = smem + (cur ^ 1) * 8192;
            const int kn = k0 + 64;
#pragma unroll
            for (int j = 0; j < 2; ++j) {
                gl_lds16(Ag + (size_t)(j*8) * Cdim + kn, &bn[(wave*2 + j) * 512]);
                gl_lds16(Bg + (size_t)(j*8) * Cdim + kn, &bn[4096 + (wave*2 + j) * 512]);
            }
        }
#pragma unroll
        for (int kc = 0; kc < 2; ++kc) {
            short8 af = *(const short8*)&bc[(wave*16 + ln)*64
                                            + ((kc*32 + quad*8) ^ xsw)];
#pragma unroll
            for (int ni = 0; ni < 4; ++ni) {
                short8 bf = *(const short8*)&bc[4096 + (ni*16 + ln)*64
                                                + ((kc*32 + quad*8) ^ xsw)];
                acc[ni] = __builtin_amdgcn_mfma_f32_16x16x32_bf16(af, bf, acc[ni], 0, 0, 0);
            }
        }
        __syncthreads();
        cur ^= 1;
    }

    // epilogue: two 32-col fp32 passes via LDS, fused bias
    float (*Csf)[36] = (float(*)[36])smem;   // 64 x 36 fp32 = 9216 B
#pragma unroll
    for (int p = 0; p < 2; ++p) {
        __syncthreads();
#pragma unroll
        for (int ni = 0; ni < 2; ++ni) {
            const int nn = p * 2 + ni;
#pragma unroll
            for (int reg = 0; reg < 4; ++reg)
                Csf[wave*16 + quad*4 + reg][ni*16 + ln] = acc[nn][reg];
        }
        __syncthreads();
#pragma unroll
        for (int j = 0; j < 2; ++j) {
            const int F = t + j * 256, r = F >> 3, c4 = F & 7;
            const int col = col0 + p * 32 + c4 * 4;
            float4 v  = *(const float4*)&Csf[r][c4 * 4];
            float4 bv = *(const float4*)&bias[col];
            *(float4*)&out[(size_t)(row0 + r) * Cdim + col] =
                make_float4(v.x + bv.x, v.y + bv.y, v.z + bv.z, v.w + bv.w);
        }
    }
}

// ---------------------------------------------------------------------------
// Kernel 2: sliding-window attention, TQ=64 per block, 4 waves (frozen from
// r17). Wave w owns 16 query rows end-to-end; K[192][64] DMA-staged
// (clamped rows, masked post-MFMA); Vt granule-swizzled overlay; register
// softmax. LDS 51.4KB; grid 768, bijective XCD swizzle.
// ---------------------------------------------------------------------------
#define TQ2  64
#define VSTn 200
#define PSTn 200

__global__ __launch_bounds__(256) void swin_attn(
    const unsigned short* __restrict__ qkvb, unsigned short* __restrict__ ab)
{
    __shared__ __align__(16) unsigned short SH[64 * VSTn];   // 25600B K/Vt overlay
    __shared__ __align__(16) unsigned short Pl[TQ2][PSTn];   // 25600B
    __shared__ float psum[TQ2];                              //   256B

    const int t  = threadIdx.x;
    const int id = blockIdx.y * 32 + blockIdx.x;   // 768 blocks
    const int p8 = id & 7, j8 = id >> 3;           // 96 per XCD
    const int bh = j8 >> 2;
    const int i0 = (p8 * 4 + (j8 & 3)) * TQ2;
    const int b  = bh / Hh, h = bh % Hh;
    const int hoff = h * Dd;

    const int lane = t & 63, wave = t >> 6;
    const int ln = lane & 15, quad = lane >> 4;
    const int lr  = lane >> 3;
    const int scw = ((lane ^ lr) & 7) * 8;   // pre-swizzled src col (shorts)
    const int xsw = (ln & 7) << 3;           // read-side XOR
    const int rV  = t >> 3, c8 = t & 7;

    // ---- Q fragments (wave's 16 query rows)
    short8 qf[2];
#pragma unroll
    for (int kc = 0; kc < 2; ++kc)
        qf[kc] = *(const short8*)&qkvb[(size_t)(b * Nseq + i0 + wave*16 + ln) * E3
                                       + hoff + kc*32 + quad*8];

    // ---- V rows -> regs (clamped; P==0 exactly on masked/OOB keys)
    uint4 vreg[6];
#pragma unroll
    for (int j = 0; j < 6; ++j) {
        int g = i0 - HALF + rV + j*32;
        g = min(max(g, 0), Nseq - 1);
        vreg[j] = *(const uint4*)&qkvb[(size_t)(b * Nseq + g) * E3 + 2*Cdim + hoff + c8*8];
    }

    // ---- K -> LDS via DMA (24 x 8-row groups; clamped rows)
#pragma unroll
    for (int j = 0; j < 6; ++j) {
        const int base = (j*4 + wave) * 8;
        int g = i0 - HALF + base + lr;
        g = min(max(g, 0), Nseq - 1);
        gl_lds16(&qkvb[(size_t)(b * Nseq + g) * E3 + Cdim + hoff + scw],
                 &SH[base * 64]);
    }
    __syncthreads();

    // ---- S phase: wave's queries need key tiles [wave, wave+8]
    f32x4 sacc[9] = {};
#pragma unroll
    for (int kc = 0; kc < 2; ++kc)
#pragma unroll
        for (int tt = 0; tt < 9; ++tt) {
            short8 kf = *(const short8*)&SH[((wave + tt)*16 + ln)*64
                                            + ((kc*32 + quad*8) ^ xsw)];
            sacc[tt] = __builtin_amdgcn_mfma_f32_16x16x32_bf16(qf[kc], kf, sacc[tt], 0, 0, 0);
        }

    // ---- mask + row max, all register-local (wave owns full rows)
    float pm[4] = {-1e30f, -1e30f, -1e30f, -1e30f};
#pragma unroll
    for (int tt = 0; tt < 9; ++tt) {
        const int r = (wave + tt)*16 + ln;
        const int g = i0 - HALF + r;
#pragma unroll
        for (int reg = 0; reg < 4; ++reg) {
            const int q = wave*16 + quad*4 + reg;
            const bool valid = (r >= q) && (r <= q + 2*HALF) && (g >= 0) && (g < Nseq);
            const float s = valid ? sacc[tt][reg] * SCALEF : -1e30f;
            sacc[tt][reg] = s;
            pm[reg] = fmaxf(pm[reg], s);
        }
    }
#pragma unroll
    for (int reg = 0; reg < 4; ++reg) {
        pm[reg] = fmaxf(pm[reg], __shfl_xor(pm[reg], 1));
        pm[reg] = fmaxf(pm[reg], __shfl_xor(pm[reg], 2));
        pm[reg] = fmaxf(pm[reg], __shfl_xor(pm[reg], 4));
        pm[reg] = fmaxf(pm[reg], __shfl_xor(pm[reg], 8));
    }
    float ps[4] = {};
#pragma unroll
    for (int reg = 0; reg < 4; ++reg)
#pragma unroll
        for (int tt = 0; tt < 9; ++tt) {
            const float pv = (sacc[tt][reg] > -1e29f) ? __expf(sacc[tt][reg] - pm[reg]) : 0.f;
            sacc[tt][reg] = pv;
            ps[reg] += pv;
        }
#pragma unroll
    for (int reg = 0; reg < 4; ++reg) {
        ps[reg] += __shfl_xor(ps[reg], 1);
        ps[reg] += __shfl_xor(ps[reg], 2);
        ps[reg] += __shfl_xor(ps[reg], 4);
        ps[reg] += __shfl_xor(ps[reg], 8);
    }

    // ---- P stores, boundary-tile zero, psum store.
#pragma unroll
    for (int tt = 0; tt < 9; ++tt)
#pragma unroll
        for (int reg = 0; reg < 4; ++reg)
            Pl[wave*16 + quad*4 + reg][(wave + tt)*16 + ln] = f2bf(sacc[tt][reg]);
    {
        const int tz = (wave & 1) ? (wave - 1) : (wave + 9);
        *(uint2*)&Pl[wave*16 + ln][tz*16 + quad*4] = make_uint2(0u, 0u);
    }
    if (ln == 0)
#pragma unroll
        for (int reg = 0; reg < 4; ++reg)
            psum[wave*16 + quad*4 + reg] = ps[reg];
    __syncthreads();   // all waves' K reads complete -> Vt overlay safe

    // ---- Vt transpose stores, granule-swizzled (2-way banks = free)
#pragma unroll
    for (int j = 0; j < 6; ++j) {
        const int r = rV + j*32;
        const int gr = ((r >> 3) ^ c8)*8 + (r & 7);
        union { unsigned short us[8]; uint4 u; } pk; pk.u = vreg[j];
#pragma unroll
        for (int d8 = 0; d8 < 8; ++d8)
            SH[(c8*8 + d8)*VSTn + gr] = pk.us[d8];
    }
    __syncthreads();

    // ---- PV: wave's own 16 queries (cols), all 64 dims, 5 kc blocks
    const int kc0 = wave >> 1;
    f32x4 oacc[4] = {};
#pragma unroll
    for (int c = 0; c < 5; ++c) {
        const int kc = kc0 + c;
        short8 pf = *(const short8*)&Pl[wave*16 + ln][kc*32 + quad*8];
#pragma unroll
        for (int m = 0; m < 4; ++m) {
            const int d = m*16 + ln;
            short8 vf = *(const short8*)&SH[d * VSTn
                                            + (((kc*4 + quad) ^ (d >> 3)) << 3)];
            oacc[m] = __builtin_amdgcn_mfma_f32_16x16x32_bf16(vf, pf, oacc[m], 0, 0, 0);
        }
    }

    const int q = wave*16 + ln;
    const float inv = 1.f / psum[q];
    unsigned short* orow = &ab[(size_t)(b * Nseq + i0 + q) * Cdim + hoff];
#pragma unroll
    for (int m = 0; m < 4; ++m) {
        const int d0 = m*16 + quad*4;
        union { unsigned short us[4]; uint2 u2; } pk;
#pragma unroll
        for (int reg = 0; reg < 4; ++reg)
            pk.us[reg] = f2bf(oacc[m][reg] * inv);
        *(uint2*)&orow[d0] = pk.u2;
    }
}

// ---------------------------------------------------------------------------
extern "C" void kernel_launch(void* const* d_in, const int* in_sizes, int n_in,
                              void* d_out, int out_size, void* d_ws, size_t ws_size,
                              hipStream_t stream)
{
    const float* x      = (const float*)d_in[0];
    const float* w_qkv  = (const float*)d_in[1];
    const float* w_proj = (const float*)d_in[2];
    const float* b_proj = (const float*)d_in[3];
    float* out = (float*)d_out;

    unsigned short* qkvb = (unsigned short*)d_ws;   // 9,437,184 shorts
    unsigned short* ab   = qkvb + 9437184;          // 3,145,728 shorts
    unsigned short* xb   = ab   + 3145728;          // 3,145,728 shorts
    unsigned short* wqb  = xb   + 3145728;          // 1,769,472 shorts
    unsigned short* wpb  = wqb  + 1769472;          //   589,824 shorts (36.2MB total)

    cvt3<<<dim3(2688), 256, 0, stream>>>(x, w_qkv, w_proj, xb, wqb, wpb);
    qkv_mfma<<<dim3(18, 32), 256, 0, stream>>>(xb, wqb, qkvb);
    swin_attn<<<dim3(32, Bsz * Hh), 256, 0, stream>>>(qkvb, ab);
    proj_mfma<<<dim3(12, 64), 256, 0, stream>>>(ab, wpb, b_proj, out);
}